// Round 11
// baseline (1139.412 us; speedup 1.0000x reference)
//
#include <hip/hip_runtime.h>
#include <hip/hip_bf16.h>
#include <cstdint>
#include <cstddef>

#define KEYSHIFT 20
#define COLMASK 0xFFFFFu
#define EPB 16384   // edges per count/scatter block (1024 threads x 16)

// ---------------------------------------------------------------------------
// Host-side reproduction of np.random.RandomState(2).permutation(64):
// MT19937 init_genrand(2), Fisher-Yates with numpy random_interval
// (mask+rejection). Mask bit d = (perm[d] >= 38).
// ---------------------------------------------------------------------------
static uint64_t compute_mask_bits() {
    uint32_t mt[624];
    mt[0] = 2u;
    for (int i = 1; i < 624; i++)
        mt[i] = 1812433253u * (mt[i - 1] ^ (mt[i - 1] >> 30)) + (uint32_t)i;
    int mti = 624;
    auto genrand = [&]() -> uint32_t {
        if (mti >= 624) {
            for (int k = 0; k < 624; k++) {
                uint32_t y = (mt[k] & 0x80000000u) | (mt[(k + 1) % 624] & 0x7fffffffu);
                mt[k] = mt[(k + 397) % 624] ^ (y >> 1) ^ ((y & 1u) ? 2567483615u : 0u);
            }
            mti = 0;
        }
        uint32_t y = mt[mti++];
        y ^= y >> 11;
        y ^= (y << 7) & 2636928640u;
        y ^= (y << 15) & 4022730752u;
        y ^= y >> 18;
        return y;
    };
    int arr[64];
    for (int i = 0; i < 64; i++) arr[i] = i;
    for (int i = 63; i >= 1; i--) {
        uint32_t mask = (uint32_t)i;
        mask |= mask >> 1; mask |= mask >> 2; mask |= mask >> 4;
        mask |= mask >> 8; mask |= mask >> 16;
        uint32_t v;
        do { v = genrand() & mask; } while (v > (uint32_t)i);
        int tmp = arr[i]; arr[i] = arr[v]; arr[v] = tmp;
    }
    uint64_t bits = 0;
    for (int d = 0; d < 64; d++)
        if (arr[d] >= 38) bits |= (1ull << d);
    return bits;
}

// ---------------------------------------------------------------------------
// Output-row flag set + compacted list (rows read by the final dot).
// ---------------------------------------------------------------------------
__global__ void flag_kernel(const int* __restrict__ users, const int* __restrict__ items,
                            unsigned char* __restrict__ flag, int B, int U) {
    int i = blockIdx.x * 256 + threadIdx.x;
    if (i < B) flag[users[i]] = 1;
    else if (i < 2 * B) flag[U + items[i - B]] = 1;
}

__global__ void flist_kernel(const unsigned char* __restrict__ flag,
                             int* __restrict__ flist, int* __restrict__ fcount, int n) {
    int i = blockIdx.x * 256 + threadIdx.x;
    if (i < n && flag[i]) {
        int p = atomicAdd(fcount, 1);
        flist[p] = i;
    }
}

// ---------------------------------------------------------------------------
// Per-rating constant c1[r][j] = b1[r][j] + sum_k e_r[k] * W1[r][64+k][j].
// ---------------------------------------------------------------------------
__global__ void c1_kernel(const float* __restrict__ rating_emb, const float* __restrict__ W1,
                          const float* __restrict__ b1, float* __restrict__ c1_all) {
    int r = blockIdx.x;
    int t = threadIdx.x;  // 64 threads
    const float* W1r = W1 + (size_t)r * (128 * 64);
    float acc = b1[r * 64 + t];
    for (int k = 0; k < 64; k++)
        acc += rating_emb[r * 64 + k] * W1r[(64 + k) * 64 + t];
    c1_all[r * 64 + t] = acc;
}

// ---------------------------------------------------------------------------
// Build pass A (batched over ratings): LDS histogram over K=ceil(N/64) row
// buckets, then ONE global atomicAdd per (block,bucket) to reserve a range.
// (global-atomic count is the cost driver: each device-scope atomic is a
// ~32B write-through at its homed L2 -- R7/R9 lesson.)
// ---------------------------------------------------------------------------
__global__ __launch_bounds__(1024) void bucket_count_kernel(
    const int* __restrict__ rows, int* __restrict__ gcnt,
    int* __restrict__ blockBase, int E, int K, int nb) {
    __shared__ int hist[2048];
    int r = blockIdx.y, blk = blockIdx.x, t = threadIdx.x;
    for (int i = t; i < K; i += 1024) hist[i] = 0;
    __syncthreads();
    size_t base = (size_t)r * E + (size_t)blk * EPB;
    int cnt = E - blk * EPB;
    if (cnt > EPB) cnt = EPB;
    for (int k = t; k < cnt; k += 1024)
        atomicAdd(&hist[rows[base + k] >> 6], 1);
    __syncthreads();
    for (int i = t; i < K; i += 1024) {
        int c = hist[i];
        int bb = (c > 0) ? atomicAdd(&gcnt[r * K + i], c) : 0;
        blockBase[((size_t)r * nb + blk) * K + i] = bb;
    }
}

// ---------------------------------------------------------------------------
// Exclusive scan of K bucket counts -> bptr[K+1] per rating (grid.x = R).
// ---------------------------------------------------------------------------
__global__ void bucket_scan_kernel(const int* __restrict__ gcnt,
                                   int* __restrict__ bptr, int K) {
    __shared__ int sh[256];
    int r = blockIdx.x;
    int t = threadIdx.x;
    int base = t * 8;
    int v[8];
    int s = 0;
    #pragma unroll
    for (int j = 0; j < 8; j++) {
        int idx = base + j;
        v[j] = (idx < K) ? gcnt[r * K + idx] : 0;
        s += v[j];
    }
    sh[t] = s;
    __syncthreads();
    for (int off = 1; off < 256; off <<= 1) {
        int x = (t >= off) ? sh[t - off] : 0;
        __syncthreads();
        sh[t] += x;
        __syncthreads();
    }
    int run = sh[t] - s;
    #pragma unroll
    for (int j = 0; j < 8; j++) {
        int idx = base + j;
        if (idx <= K) bptr[r * (K + 1) + idx] = run;
        run += v[j];
    }
}

// ---------------------------------------------------------------------------
// Build pass B (per rating): atomic-free scatter into bucket-grouped rec.
// Position = bptr[bucket] + blockBase[blk][bucket] + LDS-cursor rank.
// ---------------------------------------------------------------------------
__global__ __launch_bounds__(1024) void bucket_scatter_kernel(
    const int* __restrict__ rows, const int* __restrict__ cols,
    const float* __restrict__ vals, const int* __restrict__ bptr_r,
    const int* __restrict__ blockBase_r, uint2* __restrict__ rec,
    int E, int K, int nb) {
    __shared__ int cursor[2048];
    int blk = blockIdx.x, t = threadIdx.x;
    for (int i = t; i < K; i += 1024)
        cursor[i] = bptr_r[i] + blockBase_r[(size_t)blk * K + i];
    __syncthreads();
    size_t base = (size_t)blk * EPB;
    int cnt = E - blk * EPB;
    if (cnt > EPB) cnt = EPB;
    for (int k = t; k < cnt; k += 1024) {
        int row = rows[base + k];
        int b = row >> 6;
        int pos = atomicAdd(&cursor[b], 1);
        uint32_t key = ((uint32_t)(row & 63) << KEYSHIFT) | (uint32_t)cols[base + k];
        rec[pos] = make_uint2(key, __float_as_uint(vals[base + k]));
    }
}

// ---------------------------------------------------------------------------
// Build pass C (per rating): per-bucket counting sort by rel-row:
// rec -> srec row-sorted; emits row_ptr (rating-local offsets).
// ---------------------------------------------------------------------------
__global__ __launch_bounds__(256) void bucket_sort_kernel(
    const uint2* __restrict__ rec, uint2* __restrict__ srec,
    const int* __restrict__ bptr_r, int* __restrict__ rp_r, int K, int N) {
    __shared__ int hist[64];
    __shared__ int excl[64];
    int b = blockIdx.x;
    int t = threadIdx.x;
    if (t < 64) hist[t] = 0;
    __syncthreads();
    int start = bptr_r[b], end = bptr_r[b + 1];
    for (int e = start + t; e < end; e += 256) {
        uint2 r = rec[e];
        atomicAdd(&hist[r.x >> KEYSHIFT], 1);
    }
    __syncthreads();
    if (t == 0) {
        int run = 0;
        #pragma unroll
        for (int i = 0; i < 64; i++) { excl[i] = run; run += hist[i]; }
    }
    __syncthreads();
    if (t < 64) {
        int row = b * 64 + t;
        if (row < N) rp_r[row] = start + excl[t];
        hist[t] = 0;  // reuse as cursors
    }
    if (b == K - 1 && t == 0) rp_r[N] = bptr_r[K];
    __syncthreads();
    for (int e = start + t; e < end; e += 256) {
        uint2 r = rec[e];
        int rel = (int)(r.x >> KEYSHIFT);
        int pos = start + excl[rel] + atomicAdd(&hist[rel], 1);
        srec[pos] = r;
    }
}

// ---------------------------------------------------------------------------
// Per-rating MLP: h = leaky_relu(x @ W1a + c1) @ W2 + b2
// LDS: one W tile + one X/T tile (reused) = 33 KB; 16B-group XOR swizzle
// keeps all LDS streams conflict-free. prev = h; out_acc (flagged rows):
// init ? store : RMW-add (init at r=0 replaces the 25.6MB memset -- dot
// only ever reads flagged rows).
// ---------------------------------------------------------------------------
__global__ __launch_bounds__(256) void mlp_kernel(
    const float* __restrict__ user_emb, const float* __restrict__ item_emb,
    const float* __restrict__ W1, const float* __restrict__ W2,
    const float* __restrict__ c1_all, const float* __restrict__ b2,
    float* __restrict__ prev, float* __restrict__ out_acc,
    const unsigned char* __restrict__ flag, int r, int n_rows, int U, int init) {
    __shared__ float sW[64 * 64];   // [k][j], linear
    __shared__ float sX[64 * 64];   // [k][i], group-swizzled; reused for T
    __shared__ float sc1[64];
    __shared__ float sb2v[64];

    int t = threadIdx.x;
    int row0 = blockIdx.x * 64;
    const float* W1r = W1 + (size_t)r * (128 * 64);
    const float* W2r = W2 + (size_t)r * (64 * 64);

    #pragma unroll
    for (int q = 0; q < 4; q++) {
        int f = t + 256 * q;
        int k = f >> 4, c = (f & 15) * 4;
        *(float4*)(sW + k * 64 + c) = *(const float4*)(W1r + k * 64 + c);
    }
    #pragma unroll
    for (int q = 0; q < 4; q++) {
        int f = t + 256 * q;
        int i = f & 63;
        int c = (f >> 6) * 4;
        int nrow = row0 + i;
        float4 xv = make_float4(0.f, 0.f, 0.f, 0.f);
        if (nrow < n_rows) {
            const float* src = (nrow < U) ? (user_emb + (size_t)nrow * 64)
                                          : (item_emb + (size_t)(nrow - U) * 64);
            xv = *(const float4*)(src + c);
        }
        int gi = i >> 2, w = i & 3;
        sX[(c + 0) * 64 + 4 * (gi ^ ((c + 0) & 15)) + w] = xv.x;
        sX[(c + 1) * 64 + 4 * (gi ^ ((c + 1) & 15)) + w] = xv.y;
        sX[(c + 2) * 64 + 4 * (gi ^ ((c + 2) & 15)) + w] = xv.z;
        sX[(c + 3) * 64 + 4 * (gi ^ ((c + 3) & 15)) + w] = xv.w;
    }
    if (t < 64) sc1[t] = c1_all[r * 64 + t];
    else if (t < 128) sb2v[t - 64] = b2[r * 64 + (t - 64)];
    __syncthreads();

    int gi = t & 15;
    int i0 = gi * 4, j0 = (t >> 4) * 4;
    float acc[4][4];
    #pragma unroll
    for (int a = 0; a < 4; a++)
        #pragma unroll
        for (int b = 0; b < 4; b++) acc[a][b] = sc1[j0 + b];
    for (int k = 0; k < 64; k++) {
        float4 xv = *(const float4*)(sX + k * 64 + 4 * (gi ^ (k & 15)));
        float4 wv = *(const float4*)(sW + k * 64 + j0);
        float xs[4] = {xv.x, xv.y, xv.z, xv.w};
        float ws[4] = {wv.x, wv.y, wv.z, wv.w};
        #pragma unroll
        for (int a = 0; a < 4; a++)
            #pragma unroll
            for (int b = 0; b < 4; b++) acc[a][b] += xs[a] * ws[b];
    }
    __syncthreads();

    #pragma unroll
    for (int b = 0; b < 4; b++) {
        int k = j0 + b;
        float4 tv;
        tv.x = (acc[0][b] >= 0.f) ? acc[0][b] : 0.01f * acc[0][b];
        tv.y = (acc[1][b] >= 0.f) ? acc[1][b] : 0.01f * acc[1][b];
        tv.z = (acc[2][b] >= 0.f) ? acc[2][b] : 0.01f * acc[2][b];
        tv.w = (acc[3][b] >= 0.f) ? acc[3][b] : 0.01f * acc[3][b];
        *(float4*)(sX + k * 64 + 4 * (gi ^ (k & 15))) = tv;
    }
    #pragma unroll
    for (int q = 0; q < 4; q++) {
        int f = t + 256 * q;
        int k = f >> 4, c = (f & 15) * 4;
        *(float4*)(sW + k * 64 + c) = *(const float4*)(W2r + k * 64 + c);
    }
    __syncthreads();

    #pragma unroll
    for (int a = 0; a < 4; a++)
        #pragma unroll
        for (int b = 0; b < 4; b++) acc[a][b] = sb2v[j0 + b];
    for (int k = 0; k < 64; k++) {
        float4 xv = *(const float4*)(sX + k * 64 + 4 * (gi ^ (k & 15)));
        float4 wv = *(const float4*)(sW + k * 64 + j0);
        float xs[4] = {xv.x, xv.y, xv.z, xv.w};
        float ws[4] = {wv.x, wv.y, wv.z, wv.w};
        #pragma unroll
        for (int a = 0; a < 4; a++)
            #pragma unroll
            for (int b = 0; b < 4; b++) acc[a][b] += xs[a] * ws[b];
    }
    #pragma unroll
    for (int a = 0; a < 4; a++) {
        int nrow = row0 + i0 + a;
        if (nrow < n_rows) {
            float4 hv = make_float4(acc[a][0], acc[a][1], acc[a][2], acc[a][3]);
            *(float4*)(prev + (size_t)nrow * 64 + j0) = hv;
            if (flag[nrow]) {
                float* o = out_acc + (size_t)nrow * 64 + j0;
                if (init) {
                    *(float4*)o = hv;
                } else {
                    float4 ov = *(const float4*)o;
                    ov.x += hv.x; ov.y += hv.y; ov.z += hv.z; ov.w += hv.w;
                    *(float4*)o = ov;
                }
            }
        }
    }
}

// ---------------------------------------------------------------------------
// Gather-SpMM (layers 0/1): wave = 1 row; 4 edge-groups x 16 lanes x float4
// (full 256B row consumed per gather). 8 edges in flight per wave.
// rec loads + next stores nontemporal (keep prev lines resident in L2).
// Block->row remap gives each XCD a contiguous row range (shared rec lines).
// ---------------------------------------------------------------------------
__global__ __launch_bounds__(256) void spmm_kernel(
    const float* __restrict__ prev, float* __restrict__ next,
    float* __restrict__ out_acc, const int* __restrict__ rp,
    const uint2* __restrict__ rec, const unsigned char* __restrict__ flag, int n) {
    int nbk = (int)gridDim.x;
    int blk = (int)blockIdx.x;
    int virt = ((nbk & 7) == 0) ? ((blk & 7) * (nbk >> 3) + (blk >> 3)) : blk;
    int wave = virt * 4 + (int)(threadIdx.x >> 6);
    int lane = threadIdx.x & 63;
    if (wave >= n) return;
    int sub = lane >> 4;      // edge group 0..3
    int dl = lane & 15;       // dims [dl*4, dl*4+4)
    int s = rp[wave], e2 = rp[wave + 1];
    float ax = 0.f, ay = 0.f, az = 0.f, aw = 0.f;
    int e = s + sub;
    for (; e + 4 < e2; e += 8) {
        unsigned long long q0 = __builtin_nontemporal_load(
            (const unsigned long long*)&rec[e]);
        unsigned long long q1 = __builtin_nontemporal_load(
            (const unsigned long long*)&rec[e + 4]);
        uint32_t c0 = (uint32_t)q0 & COLMASK, c1 = (uint32_t)q1 & COLMASK;
        float4 p0 = *(const float4*)(prev + (size_t)c0 * 64 + dl * 4);
        float4 p1 = *(const float4*)(prev + (size_t)c1 * 64 + dl * 4);
        float v0 = __uint_as_float((uint32_t)(q0 >> 32));
        float v1 = __uint_as_float((uint32_t)(q1 >> 32));
        ax += v0 * p0.x; ay += v0 * p0.y; az += v0 * p0.z; aw += v0 * p0.w;
        ax += v1 * p1.x; ay += v1 * p1.y; az += v1 * p1.z; aw += v1 * p1.w;
    }
    if (e < e2) {
        unsigned long long q0 = __builtin_nontemporal_load(
            (const unsigned long long*)&rec[e]);
        uint32_t c0 = (uint32_t)q0 & COLMASK;
        float4 p0 = *(const float4*)(prev + (size_t)c0 * 64 + dl * 4);
        float v0 = __uint_as_float((uint32_t)(q0 >> 32));
        ax += v0 * p0.x; ay += v0 * p0.y; az += v0 * p0.z; aw += v0 * p0.w;
    }
    ax += __shfl_xor(ax, 16); ay += __shfl_xor(ay, 16);
    az += __shfl_xor(az, 16); aw += __shfl_xor(aw, 16);
    ax += __shfl_xor(ax, 32); ay += __shfl_xor(ay, 32);
    az += __shfl_xor(az, 32); aw += __shfl_xor(aw, 32);
    if (sub == 0) {
        float* o = next + (size_t)wave * 64 + dl * 4;
        __builtin_nontemporal_store(ax, o + 0);
        __builtin_nontemporal_store(ay, o + 1);
        __builtin_nontemporal_store(az, o + 2);
        __builtin_nontemporal_store(aw, o + 3);
    } else if (sub == 1 && flag[wave]) {
        float* o = out_acc + (size_t)wave * 64 + dl * 4;
        float4 ov = *(const float4*)o;
        ov.x += ax; ov.y += ay; ov.z += az; ov.w += aw;
        *(float4*)o = ov;
    }
}

// ---------------------------------------------------------------------------
// Layer-2 (masked) SpMM: only rows in flist. Same float4-lane layout.
// ---------------------------------------------------------------------------
__global__ __launch_bounds__(256) void spmm_masked_kernel(
    const float* __restrict__ prev, float* __restrict__ out_acc,
    const int* __restrict__ rp, const uint2* __restrict__ rec,
    unsigned long long maskbits, const int* __restrict__ flist,
    const int* __restrict__ fcount) {
    int w = (int)((blockIdx.x * (unsigned)blockDim.x + threadIdx.x) >> 6);
    int lane = threadIdx.x & 63;
    if (w >= *fcount) return;
    int sub = lane >> 4;
    int dl = lane & 15;
    int row = flist[w];
    int s = rp[row], e2 = rp[row + 1];
    float ax = 0.f, ay = 0.f, az = 0.f, aw = 0.f;
    int e = s + sub;
    for (; e + 4 < e2; e += 8) {
        unsigned long long q0 = __builtin_nontemporal_load(
            (const unsigned long long*)&rec[e]);
        unsigned long long q1 = __builtin_nontemporal_load(
            (const unsigned long long*)&rec[e + 4]);
        uint32_t c0 = (uint32_t)q0 & COLMASK, c1 = (uint32_t)q1 & COLMASK;
        float4 p0 = *(const float4*)(prev + (size_t)c0 * 64 + dl * 4);
        float4 p1 = *(const float4*)(prev + (size_t)c1 * 64 + dl * 4);
        float v0 = __uint_as_float((uint32_t)(q0 >> 32));
        float v1 = __uint_as_float((uint32_t)(q1 >> 32));
        ax += v0 * p0.x; ay += v0 * p0.y; az += v0 * p0.z; aw += v0 * p0.w;
        ax += v1 * p1.x; ay += v1 * p1.y; az += v1 * p1.z; aw += v1 * p1.w;
    }
    if (e < e2) {
        unsigned long long q0 = __builtin_nontemporal_load(
            (const unsigned long long*)&rec[e]);
        uint32_t c0 = (uint32_t)q0 & COLMASK;
        float4 p0 = *(const float4*)(prev + (size_t)c0 * 64 + dl * 4);
        float v0 = __uint_as_float((uint32_t)(q0 >> 32));
        ax += v0 * p0.x; ay += v0 * p0.y; az += v0 * p0.z; aw += v0 * p0.w;
    }
    ax += __shfl_xor(ax, 16); ay += __shfl_xor(ay, 16);
    az += __shfl_xor(az, 16); aw += __shfl_xor(aw, 16);
    ax += __shfl_xor(ax, 32); ay += __shfl_xor(ay, 32);
    az += __shfl_xor(az, 32); aw += __shfl_xor(aw, 32);
    if (sub == 0) {
        const float* pv = prev + (size_t)row * 64 + dl * 4;
        float4 pvv = *(const float4*)pv;
        float rx = ((maskbits >> (dl * 4 + 0)) & 1ull) ? ax : pvv.x;
        float ry = ((maskbits >> (dl * 4 + 1)) & 1ull) ? ay : pvv.y;
        float rz = ((maskbits >> (dl * 4 + 2)) & 1ull) ? az : pvv.z;
        float rw = ((maskbits >> (dl * 4 + 3)) & 1ull) ? aw : pvv.w;
        float* o = out_acc + (size_t)row * 64 + dl * 4;
        float4 ov = *(const float4*)o;
        ov.x += rx; ov.y += ry; ov.z += rz; ov.w += rw;
        *(float4*)o = ov;
    }
}

// ---------------------------------------------------------------------------
// Final: out[b] = (1/R^2) * dot(out_acc[users[b]], out_acc[U+items[b]])
// ---------------------------------------------------------------------------
__global__ __launch_bounds__(256) void dot_kernel(
    const float* __restrict__ out_acc, const int* __restrict__ users,
    const int* __restrict__ items, float* __restrict__ out,
    int Bn, int U, float scale) {
    int w = (int)((blockIdx.x * (unsigned)blockDim.x + threadIdx.x) >> 6);
    int lane = threadIdx.x & 63;
    if (w >= Bn) return;
    int u = users[w], it = items[w];
    float a = out_acc[(size_t)u * 64 + lane];
    float c = out_acc[((size_t)(U + it)) * 64 + lane];
    float p = a * c;
    #pragma unroll
    for (int off = 32; off > 0; off >>= 1) p += __shfl_down(p, off);
    if (lane == 0) out[w] = p * scale;
}

// ---------------------------------------------------------------------------
extern "C" void kernel_launch(void* const* d_in, const int* in_sizes, int n_in,
                              void* d_out, int out_size, void* d_ws, size_t ws_size,
                              hipStream_t stream) {
    const int* users = (const int*)d_in[0];
    const int* items = (const int*)d_in[1];
    const float* user_emb = (const float*)d_in[2];
    const float* item_emb = (const float*)d_in[3];
    const float* rating_emb = (const float*)d_in[4];
    const float* W1 = (const float*)d_in[5];
    const float* b1 = (const float*)d_in[6];
    const float* W2 = (const float*)d_in[7];
    const float* b2 = (const float*)d_in[8];
    const int* rows = (const int*)d_in[9];
    const int* cols = (const int*)d_in[10];
    const float* vals = (const float*)d_in[11];
    float* out = (float*)d_out;

    const int Dd = 64;
    int U = in_sizes[2] / Dd;
    int I = in_sizes[3] / Dd;
    int R = in_sizes[4] / Dd;
    int N = U + I;
    int E = in_sizes[9] / R;
    int Bn = in_sizes[0];
    int K = (N + 63) / 64;          // row buckets; K+1 <= 2048
    int nb = (E + EPB - 1) / EPB;   // count/scatter blocks per rating

    char* p = (char*)d_ws;
    auto carve = [&](size_t bytes) -> char* {
        char* q = p;
        p += (bytes + 255) & ~(size_t)255;
        return q;
    };
    float* out_acc = (float*)carve((size_t)N * 64 * 4);
    float* bufA = (float*)carve((size_t)N * 64 * 4);
    float* bufB = (float*)carve((size_t)N * 64 * 4);
    uint2* rec = (uint2*)carve((size_t)E * 8);
    uint2* srec = (uint2*)carve((size_t)E * 8);
    int* gcnt = (int*)carve((size_t)R * K * 4);
    int* bptr = (int*)carve((size_t)R * (K + 1) * 4);
    int* blockBase = (int*)carve((size_t)R * nb * K * 4);
    int* row_ptr = (int*)carve((size_t)R * (N + 1) * 4);
    float* c1_all = (float*)carve((size_t)R * 64 * 4);
    unsigned char* flag = (unsigned char*)carve((size_t)N);
    int* flist = (int*)carve((size_t)2 * Bn * 4);
    int* fcount = (int*)carve(4);

    uint64_t maskbits = compute_mask_bits();

    hipMemsetAsync(flag, 0, (size_t)N, stream);
    hipMemsetAsync(fcount, 0, 4, stream);
    hipMemsetAsync(gcnt, 0, (size_t)R * K * 4, stream);

    flag_kernel<<<(2 * Bn + 255) / 256, 256, 0, stream>>>(users, items, flag, Bn, U);
    flist_kernel<<<(N + 255) / 256, 256, 0, stream>>>(flag, flist, fcount, N);
    c1_kernel<<<R, 64, 0, stream>>>(rating_emb, W1, b1, c1_all);

    // Build pass A (batched) + per-rating scans
    dim3 cgrid(nb, R);
    bucket_count_kernel<<<cgrid, 1024, 0, stream>>>(rows, gcnt, blockBase, E, K, nb);
    bucket_scan_kernel<<<R, 256, 0, stream>>>(gcnt, bptr, K);

    int spmm_blocks = (N + 3) / 4;
    int masked_blocks = (2 * Bn + 3) / 4;
    for (int r = 0; r < R; r++) {
        const int* rows_r = rows + (size_t)r * E;
        const int* cols_r = cols + (size_t)r * E;
        const float* vals_r = vals + (size_t)r * E;
        const int* bptr_r = bptr + (size_t)r * (K + 1);
        const int* blockBase_r = blockBase + (size_t)r * nb * K;
        int* rp_r = row_ptr + (size_t)r * (N + 1);

        bucket_scatter_kernel<<<nb, 1024, 0, stream>>>(rows_r, cols_r, vals_r,
                                                       bptr_r, blockBase_r, rec,
                                                       E, K, nb);
        bucket_sort_kernel<<<K, 256, 0, stream>>>(rec, srec, bptr_r, rp_r, K, N);

        mlp_kernel<<<(N + 63) / 64, 256, 0, stream>>>(user_emb, item_emb, W1, W2,
                                                      c1_all, b2, bufA, out_acc,
                                                      flag, r, N, U, (r == 0) ? 1 : 0);

        spmm_kernel<<<spmm_blocks, 256, 0, stream>>>(bufA, bufB, out_acc, rp_r,
                                                     srec, flag, N);
        spmm_kernel<<<spmm_blocks, 256, 0, stream>>>(bufB, bufA, out_acc, rp_r,
                                                     srec, flag, N);
        spmm_masked_kernel<<<masked_blocks, 256, 0, stream>>>(bufA, out_acc, rp_r,
                                                              srec, maskbits,
                                                              flist, fcount);
    }

    float scale = 1.0f / (float)(R * R);
    dot_kernel<<<(Bn * 64 + 255) / 256, 256, 0, stream>>>(out_acc, users, items, out,
                                                          Bn, U, scale);
}

// Round 12
// 1070.250 us; speedup vs baseline: 1.0646x; 1.0646x over previous
//
#include <hip/hip_runtime.h>
#include <hip/hip_bf16.h>
#include <cstdint>
#include <cstddef>

#define KEYSHIFT 20
#define COLMASK 0xFFFFFu
#define EPB 16384   // edges per count/scatter block (1024 threads x 16)

// ---------------------------------------------------------------------------
// Host-side reproduction of np.random.RandomState(2).permutation(64):
// MT19937 init_genrand(2), Fisher-Yates with numpy random_interval
// (mask+rejection). Mask bit d = (perm[d] >= 38).
// ---------------------------------------------------------------------------
static uint64_t compute_mask_bits() {
    uint32_t mt[624];
    mt[0] = 2u;
    for (int i = 1; i < 624; i++)
        mt[i] = 1812433253u * (mt[i - 1] ^ (mt[i - 1] >> 30)) + (uint32_t)i;
    int mti = 624;
    auto genrand = [&]() -> uint32_t {
        if (mti >= 624) {
            for (int k = 0; k < 624; k++) {
                uint32_t y = (mt[k] & 0x80000000u) | (mt[(k + 1) % 624] & 0x7fffffffu);
                mt[k] = mt[(k + 397) % 624] ^ (y >> 1) ^ ((y & 1u) ? 2567483615u : 0u);
            }
            mti = 0;
        }
        uint32_t y = mt[mti++];
        y ^= y >> 11;
        y ^= (y << 7) & 2636928640u;
        y ^= (y << 15) & 4022730752u;
        y ^= y >> 18;
        return y;
    };
    int arr[64];
    for (int i = 0; i < 64; i++) arr[i] = i;
    for (int i = 63; i >= 1; i--) {
        uint32_t mask = (uint32_t)i;
        mask |= mask >> 1; mask |= mask >> 2; mask |= mask >> 4;
        mask |= mask >> 8; mask |= mask >> 16;
        uint32_t v;
        do { v = genrand() & mask; } while (v > (uint32_t)i);
        int tmp = arr[i]; arr[i] = arr[v]; arr[v] = tmp;
    }
    uint64_t bits = 0;
    for (int d = 0; d < 64; d++)
        if (arr[d] >= 38) bits |= (1ull << d);
    return bits;
}

// ---------------------------------------------------------------------------
// Output-row flag set + compacted list (rows read by the final dot).
// ---------------------------------------------------------------------------
__global__ void flag_kernel(const int* __restrict__ users, const int* __restrict__ items,
                            unsigned char* __restrict__ flag, int B, int U) {
    int i = blockIdx.x * 256 + threadIdx.x;
    if (i < B) flag[users[i]] = 1;
    else if (i < 2 * B) flag[U + items[i - B]] = 1;
}

__global__ void flist_kernel(const unsigned char* __restrict__ flag,
                             int* __restrict__ flist, int* __restrict__ fcount, int n) {
    int i = blockIdx.x * 256 + threadIdx.x;
    if (i < n && flag[i]) {
        int p = atomicAdd(fcount, 1);
        flist[p] = i;
    }
}

// ---------------------------------------------------------------------------
// Per-rating constant c1[r][j] = b1[r][j] + sum_k e_r[k] * W1[r][64+k][j].
// ---------------------------------------------------------------------------
__global__ void c1_kernel(const float* __restrict__ rating_emb, const float* __restrict__ W1,
                          const float* __restrict__ b1, float* __restrict__ c1_all) {
    int r = blockIdx.x;
    int t = threadIdx.x;  // 64 threads
    const float* W1r = W1 + (size_t)r * (128 * 64);
    float acc = b1[r * 64 + t];
    for (int k = 0; k < 64; k++)
        acc += rating_emb[r * 64 + k] * W1r[(64 + k) * 64 + t];
    c1_all[r * 64 + t] = acc;
}

// ---------------------------------------------------------------------------
// Build pass A (batched over ratings): LDS histogram over K=ceil(N/64) row
// buckets, then ONE global atomicAdd per (block,bucket) to reserve a range.
// (global-atomic count is the cost driver: each device-scope atomic is a
// ~32B write-through at its homed L2 -- R7/R9 lesson.)
// ---------------------------------------------------------------------------
__global__ __launch_bounds__(1024) void bucket_count_kernel(
    const int* __restrict__ rows, int* __restrict__ gcnt,
    int* __restrict__ blockBase, int E, int K, int nb) {
    __shared__ int hist[2048];
    int r = blockIdx.y, blk = blockIdx.x, t = threadIdx.x;
    for (int i = t; i < K; i += 1024) hist[i] = 0;
    __syncthreads();
    size_t base = (size_t)r * E + (size_t)blk * EPB;
    int cnt = E - blk * EPB;
    if (cnt > EPB) cnt = EPB;
    for (int k = t; k < cnt; k += 1024)
        atomicAdd(&hist[rows[base + k] >> 6], 1);
    __syncthreads();
    for (int i = t; i < K; i += 1024) {
        int c = hist[i];
        int bb = (c > 0) ? atomicAdd(&gcnt[r * K + i], c) : 0;
        blockBase[((size_t)r * nb + blk) * K + i] = bb;
    }
}

// ---------------------------------------------------------------------------
// Exclusive scan of K bucket counts -> bptr[K+1] per rating (grid.x = R).
// ---------------------------------------------------------------------------
__global__ void bucket_scan_kernel(const int* __restrict__ gcnt,
                                   int* __restrict__ bptr, int K) {
    __shared__ int sh[256];
    int r = blockIdx.x;
    int t = threadIdx.x;
    int base = t * 8;
    int v[8];
    int s = 0;
    #pragma unroll
    for (int j = 0; j < 8; j++) {
        int idx = base + j;
        v[j] = (idx < K) ? gcnt[r * K + idx] : 0;
        s += v[j];
    }
    sh[t] = s;
    __syncthreads();
    for (int off = 1; off < 256; off <<= 1) {
        int x = (t >= off) ? sh[t - off] : 0;
        __syncthreads();
        sh[t] += x;
        __syncthreads();
    }
    int run = sh[t] - s;
    #pragma unroll
    for (int j = 0; j < 8; j++) {
        int idx = base + j;
        if (idx <= K) bptr[r * (K + 1) + idx] = run;
        run += v[j];
    }
}

// ---------------------------------------------------------------------------
// Build pass B (per rating): atomic-free scatter into bucket-grouped rec.
// Position = bptr[bucket] + blockBase[blk][bucket] + LDS-cursor rank.
// ---------------------------------------------------------------------------
__global__ __launch_bounds__(1024) void bucket_scatter_kernel(
    const int* __restrict__ rows, const int* __restrict__ cols,
    const float* __restrict__ vals, const int* __restrict__ bptr_r,
    const int* __restrict__ blockBase_r, uint2* __restrict__ rec,
    int E, int K, int nb) {
    __shared__ int cursor[2048];
    int blk = blockIdx.x, t = threadIdx.x;
    for (int i = t; i < K; i += 1024)
        cursor[i] = bptr_r[i] + blockBase_r[(size_t)blk * K + i];
    __syncthreads();
    size_t base = (size_t)blk * EPB;
    int cnt = E - blk * EPB;
    if (cnt > EPB) cnt = EPB;
    for (int k = t; k < cnt; k += 1024) {
        int row = rows[base + k];
        int b = row >> 6;
        int pos = atomicAdd(&cursor[b], 1);
        uint32_t key = ((uint32_t)(row & 63) << KEYSHIFT) | (uint32_t)cols[base + k];
        rec[pos] = make_uint2(key, __float_as_uint(vals[base + k]));
    }
}

// ---------------------------------------------------------------------------
// Build pass C (per rating): per-bucket counting sort by rel-row:
// rec -> srec row-sorted; emits row_ptr (rating-local offsets).
// ---------------------------------------------------------------------------
__global__ __launch_bounds__(256) void bucket_sort_kernel(
    const uint2* __restrict__ rec, uint2* __restrict__ srec,
    const int* __restrict__ bptr_r, int* __restrict__ rp_r, int K, int N) {
    __shared__ int hist[64];
    __shared__ int excl[64];
    int b = blockIdx.x;
    int t = threadIdx.x;
    if (t < 64) hist[t] = 0;
    __syncthreads();
    int start = bptr_r[b], end = bptr_r[b + 1];
    for (int e = start + t; e < end; e += 256) {
        uint2 r = rec[e];
        atomicAdd(&hist[r.x >> KEYSHIFT], 1);
    }
    __syncthreads();
    if (t == 0) {
        int run = 0;
        #pragma unroll
        for (int i = 0; i < 64; i++) { excl[i] = run; run += hist[i]; }
    }
    __syncthreads();
    if (t < 64) {
        int row = b * 64 + t;
        if (row < N) rp_r[row] = start + excl[t];
        hist[t] = 0;  // reuse as cursors
    }
    if (b == K - 1 && t == 0) rp_r[N] = bptr_r[K];
    __syncthreads();
    for (int e = start + t; e < end; e += 256) {
        uint2 r = rec[e];
        int rel = (int)(r.x >> KEYSHIFT);
        int pos = start + excl[rel] + atomicAdd(&hist[rel], 1);
        srec[pos] = r;
    }
}

// ---------------------------------------------------------------------------
// Per-rating MLP: h = leaky_relu(x @ W1a + c1) @ W2 + b2
// LDS: one W tile + one X/T tile (reused) = 33 KB; 16B-group XOR swizzle
// keeps all LDS streams conflict-free. prev = h; out_acc (flagged rows):
// init ? store : RMW-add (init at r=0 replaces the 25.6MB memset -- dot
// only ever reads flagged rows).
// ---------------------------------------------------------------------------
__global__ __launch_bounds__(256) void mlp_kernel(
    const float* __restrict__ user_emb, const float* __restrict__ item_emb,
    const float* __restrict__ W1, const float* __restrict__ W2,
    const float* __restrict__ c1_all, const float* __restrict__ b2,
    float* __restrict__ prev, float* __restrict__ out_acc,
    const unsigned char* __restrict__ flag, int r, int n_rows, int U, int init) {
    __shared__ float sW[64 * 64];   // [k][j], linear
    __shared__ float sX[64 * 64];   // [k][i], group-swizzled; reused for T
    __shared__ float sc1[64];
    __shared__ float sb2v[64];

    int t = threadIdx.x;
    int row0 = blockIdx.x * 64;
    const float* W1r = W1 + (size_t)r * (128 * 64);
    const float* W2r = W2 + (size_t)r * (64 * 64);

    #pragma unroll
    for (int q = 0; q < 4; q++) {
        int f = t + 256 * q;
        int k = f >> 4, c = (f & 15) * 4;
        *(float4*)(sW + k * 64 + c) = *(const float4*)(W1r + k * 64 + c);
    }
    #pragma unroll
    for (int q = 0; q < 4; q++) {
        int f = t + 256 * q;
        int i = f & 63;
        int c = (f >> 6) * 4;
        int nrow = row0 + i;
        float4 xv = make_float4(0.f, 0.f, 0.f, 0.f);
        if (nrow < n_rows) {
            const float* src = (nrow < U) ? (user_emb + (size_t)nrow * 64)
                                          : (item_emb + (size_t)(nrow - U) * 64);
            xv = *(const float4*)(src + c);
        }
        int gi = i >> 2, w = i & 3;
        sX[(c + 0) * 64 + 4 * (gi ^ ((c + 0) & 15)) + w] = xv.x;
        sX[(c + 1) * 64 + 4 * (gi ^ ((c + 1) & 15)) + w] = xv.y;
        sX[(c + 2) * 64 + 4 * (gi ^ ((c + 2) & 15)) + w] = xv.z;
        sX[(c + 3) * 64 + 4 * (gi ^ ((c + 3) & 15)) + w] = xv.w;
    }
    if (t < 64) sc1[t] = c1_all[r * 64 + t];
    else if (t < 128) sb2v[t - 64] = b2[r * 64 + (t - 64)];
    __syncthreads();

    int gi = t & 15;
    int i0 = gi * 4, j0 = (t >> 4) * 4;
    float acc[4][4];
    #pragma unroll
    for (int a = 0; a < 4; a++)
        #pragma unroll
        for (int b = 0; b < 4; b++) acc[a][b] = sc1[j0 + b];
    for (int k = 0; k < 64; k++) {
        float4 xv = *(const float4*)(sX + k * 64 + 4 * (gi ^ (k & 15)));
        float4 wv = *(const float4*)(sW + k * 64 + j0);
        float xs[4] = {xv.x, xv.y, xv.z, xv.w};
        float ws[4] = {wv.x, wv.y, wv.z, wv.w};
        #pragma unroll
        for (int a = 0; a < 4; a++)
            #pragma unroll
            for (int b = 0; b < 4; b++) acc[a][b] += xs[a] * ws[b];
    }
    __syncthreads();

    #pragma unroll
    for (int b = 0; b < 4; b++) {
        int k = j0 + b;
        float4 tv;
        tv.x = (acc[0][b] >= 0.f) ? acc[0][b] : 0.01f * acc[0][b];
        tv.y = (acc[1][b] >= 0.f) ? acc[1][b] : 0.01f * acc[1][b];
        tv.z = (acc[2][b] >= 0.f) ? acc[2][b] : 0.01f * acc[2][b];
        tv.w = (acc[3][b] >= 0.f) ? acc[3][b] : 0.01f * acc[3][b];
        *(float4*)(sX + k * 64 + 4 * (gi ^ (k & 15))) = tv;
    }
    #pragma unroll
    for (int q = 0; q < 4; q++) {
        int f = t + 256 * q;
        int k = f >> 4, c = (f & 15) * 4;
        *(float4*)(sW + k * 64 + c) = *(const float4*)(W2r + k * 64 + c);
    }
    __syncthreads();

    #pragma unroll
    for (int a = 0; a < 4; a++)
        #pragma unroll
        for (int b = 0; b < 4; b++) acc[a][b] = sb2v[j0 + b];
    for (int k = 0; k < 64; k++) {
        float4 xv = *(const float4*)(sX + k * 64 + 4 * (gi ^ (k & 15)));
        float4 wv = *(const float4*)(sW + k * 64 + j0);
        float xs[4] = {xv.x, xv.y, xv.z, xv.w};
        float ws[4] = {wv.x, wv.y, wv.z, wv.w};
        #pragma unroll
        for (int a = 0; a < 4; a++)
            #pragma unroll
            for (int b = 0; b < 4; b++) acc[a][b] += xs[a] * ws[b];
    }
    #pragma unroll
    for (int a = 0; a < 4; a++) {
        int nrow = row0 + i0 + a;
        if (nrow < n_rows) {
            float4 hv = make_float4(acc[a][0], acc[a][1], acc[a][2], acc[a][3]);
            *(float4*)(prev + (size_t)nrow * 64 + j0) = hv;
            if (flag[nrow]) {
                float* o = out_acc + (size_t)nrow * 64 + j0;
                if (init) {
                    *(float4*)o = hv;
                } else {
                    float4 ov = *(const float4*)o;
                    ov.x += hv.x; ov.y += hv.y; ov.z += hv.z; ov.w += hv.w;
                    *(float4*)o = ov;
                }
            }
        }
    }
}

// ---------------------------------------------------------------------------
// Gather-SpMM (layers 0/1): wave = 1 row; 4 edge-groups x 16 lanes x float4
// (full 256B row consumed per gather). 8 edges in flight per wave.
// R10 form exactly: plain uint2 loads, plain float4 store (NT hints and
// block remap regressed in R11 -- rec lines have cross-wave reuse).
// ---------------------------------------------------------------------------
__global__ __launch_bounds__(256) void spmm_kernel(
    const float* __restrict__ prev, float* __restrict__ next,
    float* __restrict__ out_acc, const int* __restrict__ rp,
    const uint2* __restrict__ rec, const unsigned char* __restrict__ flag, int n) {
    int wave = (int)((blockIdx.x * (unsigned)blockDim.x + threadIdx.x) >> 6);
    int lane = threadIdx.x & 63;
    if (wave >= n) return;
    int sub = lane >> 4;      // edge group 0..3
    int dl = lane & 15;       // dims [dl*4, dl*4+4)
    int s = rp[wave], e2 = rp[wave + 1];
    float ax = 0.f, ay = 0.f, az = 0.f, aw = 0.f;
    int e = s + sub;
    for (; e + 4 < e2; e += 8) {
        uint2 r0 = rec[e];
        uint2 r1 = rec[e + 4];
        float4 p0 = *(const float4*)(prev + (size_t)(r0.x & COLMASK) * 64 + dl * 4);
        float4 p1 = *(const float4*)(prev + (size_t)(r1.x & COLMASK) * 64 + dl * 4);
        float v0 = __uint_as_float(r0.y), v1 = __uint_as_float(r1.y);
        ax += v0 * p0.x; ay += v0 * p0.y; az += v0 * p0.z; aw += v0 * p0.w;
        ax += v1 * p1.x; ay += v1 * p1.y; az += v1 * p1.z; aw += v1 * p1.w;
    }
    if (e < e2) {
        uint2 r0 = rec[e];
        float4 p0 = *(const float4*)(prev + (size_t)(r0.x & COLMASK) * 64 + dl * 4);
        float v0 = __uint_as_float(r0.y);
        ax += v0 * p0.x; ay += v0 * p0.y; az += v0 * p0.z; aw += v0 * p0.w;
    }
    ax += __shfl_xor(ax, 16); ay += __shfl_xor(ay, 16);
    az += __shfl_xor(az, 16); aw += __shfl_xor(aw, 16);
    ax += __shfl_xor(ax, 32); ay += __shfl_xor(ay, 32);
    az += __shfl_xor(az, 32); aw += __shfl_xor(aw, 32);
    if (sub == 0) {
        *(float4*)(next + (size_t)wave * 64 + dl * 4) = make_float4(ax, ay, az, aw);
    } else if (sub == 1 && flag[wave]) {
        float* o = out_acc + (size_t)wave * 64 + dl * 4;
        float4 ov = *(const float4*)o;
        ov.x += ax; ov.y += ay; ov.z += az; ov.w += aw;
        *(float4*)o = ov;
    }
}

// ---------------------------------------------------------------------------
// Layer-2 (masked) SpMM: only rows in flist. Same float4-lane layout.
// ---------------------------------------------------------------------------
__global__ __launch_bounds__(256) void spmm_masked_kernel(
    const float* __restrict__ prev, float* __restrict__ out_acc,
    const int* __restrict__ rp, const uint2* __restrict__ rec,
    unsigned long long maskbits, const int* __restrict__ flist,
    const int* __restrict__ fcount) {
    int w = (int)((blockIdx.x * (unsigned)blockDim.x + threadIdx.x) >> 6);
    int lane = threadIdx.x & 63;
    if (w >= *fcount) return;
    int sub = lane >> 4;
    int dl = lane & 15;
    int row = flist[w];
    int s = rp[row], e2 = rp[row + 1];
    float ax = 0.f, ay = 0.f, az = 0.f, aw = 0.f;
    int e = s + sub;
    for (; e + 4 < e2; e += 8) {
        uint2 r0 = rec[e];
        uint2 r1 = rec[e + 4];
        float4 p0 = *(const float4*)(prev + (size_t)(r0.x & COLMASK) * 64 + dl * 4);
        float4 p1 = *(const float4*)(prev + (size_t)(r1.x & COLMASK) * 64 + dl * 4);
        float v0 = __uint_as_float(r0.y), v1 = __uint_as_float(r1.y);
        ax += v0 * p0.x; ay += v0 * p0.y; az += v0 * p0.z; aw += v0 * p0.w;
        ax += v1 * p1.x; ay += v1 * p1.y; az += v1 * p1.z; aw += v1 * p1.w;
    }
    if (e < e2) {
        uint2 r0 = rec[e];
        float4 p0 = *(const float4*)(prev + (size_t)(r0.x & COLMASK) * 64 + dl * 4);
        float v0 = __uint_as_float(r0.y);
        ax += v0 * p0.x; ay += v0 * p0.y; az += v0 * p0.z; aw += v0 * p0.w;
    }
    ax += __shfl_xor(ax, 16); ay += __shfl_xor(ay, 16);
    az += __shfl_xor(az, 16); aw += __shfl_xor(aw, 16);
    ax += __shfl_xor(ax, 32); ay += __shfl_xor(ay, 32);
    az += __shfl_xor(az, 32); aw += __shfl_xor(aw, 32);
    if (sub == 0) {
        const float* pv = prev + (size_t)row * 64 + dl * 4;
        float4 pvv = *(const float4*)pv;
        float rx = ((maskbits >> (dl * 4 + 0)) & 1ull) ? ax : pvv.x;
        float ry = ((maskbits >> (dl * 4 + 1)) & 1ull) ? ay : pvv.y;
        float rz = ((maskbits >> (dl * 4 + 2)) & 1ull) ? az : pvv.z;
        float rw = ((maskbits >> (dl * 4 + 3)) & 1ull) ? aw : pvv.w;
        float* o = out_acc + (size_t)row * 64 + dl * 4;
        float4 ov = *(const float4*)o;
        ov.x += rx; ov.y += ry; ov.z += rz; ov.w += rw;
        *(float4*)o = ov;
    }
}

// ---------------------------------------------------------------------------
// Final: out[b] = (1/R^2) * dot(out_acc[users[b]], out_acc[U+items[b]])
// ---------------------------------------------------------------------------
__global__ __launch_bounds__(256) void dot_kernel(
    const float* __restrict__ out_acc, const int* __restrict__ users,
    const int* __restrict__ items, float* __restrict__ out,
    int Bn, int U, float scale) {
    int w = (int)((blockIdx.x * (unsigned)blockDim.x + threadIdx.x) >> 6);
    int lane = threadIdx.x & 63;
    if (w >= Bn) return;
    int u = users[w], it = items[w];
    float a = out_acc[(size_t)u * 64 + lane];
    float c = out_acc[((size_t)(U + it)) * 64 + lane];
    float p = a * c;
    #pragma unroll
    for (int off = 32; off > 0; off >>= 1) p += __shfl_down(p, off);
    if (lane == 0) out[w] = p * scale;
}

// ---------------------------------------------------------------------------
extern "C" void kernel_launch(void* const* d_in, const int* in_sizes, int n_in,
                              void* d_out, int out_size, void* d_ws, size_t ws_size,
                              hipStream_t stream) {
    const int* users = (const int*)d_in[0];
    const int* items = (const int*)d_in[1];
    const float* user_emb = (const float*)d_in[2];
    const float* item_emb = (const float*)d_in[3];
    const float* rating_emb = (const float*)d_in[4];
    const float* W1 = (const float*)d_in[5];
    const float* b1 = (const float*)d_in[6];
    const float* W2 = (const float*)d_in[7];
    const float* b2 = (const float*)d_in[8];
    const int* rows = (const int*)d_in[9];
    const int* cols = (const int*)d_in[10];
    const float* vals = (const float*)d_in[11];
    float* out = (float*)d_out;

    const int Dd = 64;
    int U = in_sizes[2] / Dd;
    int I = in_sizes[3] / Dd;
    int R = in_sizes[4] / Dd;
    int N = U + I;
    int E = in_sizes[9] / R;
    int Bn = in_sizes[0];
    int K = (N + 63) / 64;          // row buckets; K+1 <= 2048
    int nb = (E + EPB - 1) / EPB;   // count/scatter blocks per rating

    char* p = (char*)d_ws;
    auto carve = [&](size_t bytes) -> char* {
        char* q = p;
        p += (bytes + 255) & ~(size_t)255;
        return q;
    };
    float* out_acc = (float*)carve((size_t)N * 64 * 4);
    float* bufA = (float*)carve((size_t)N * 64 * 4);
    float* bufB = (float*)carve((size_t)N * 64 * 4);
    uint2* rec = (uint2*)carve((size_t)E * 8);
    uint2* srec = (uint2*)carve((size_t)E * 8);
    int* gcnt = (int*)carve((size_t)R * K * 4);
    int* bptr = (int*)carve((size_t)R * (K + 1) * 4);
    int* blockBase = (int*)carve((size_t)R * nb * K * 4);
    int* row_ptr = (int*)carve((size_t)R * (N + 1) * 4);
    float* c1_all = (float*)carve((size_t)R * 64 * 4);
    unsigned char* flag = (unsigned char*)carve((size_t)N);
    int* flist = (int*)carve((size_t)2 * Bn * 4);
    int* fcount = (int*)carve(4);

    uint64_t maskbits = compute_mask_bits();

    hipMemsetAsync(flag, 0, (size_t)N, stream);
    hipMemsetAsync(fcount, 0, 4, stream);
    hipMemsetAsync(gcnt, 0, (size_t)R * K * 4, stream);

    flag_kernel<<<(2 * Bn + 255) / 256, 256, 0, stream>>>(users, items, flag, Bn, U);
    flist_kernel<<<(N + 255) / 256, 256, 0, stream>>>(flag, flist, fcount, N);
    c1_kernel<<<R, 64, 0, stream>>>(rating_emb, W1, b1, c1_all);

    // Build pass A (batched) + per-rating scans
    dim3 cgrid(nb, R);
    bucket_count_kernel<<<cgrid, 1024, 0, stream>>>(rows, gcnt, blockBase, E, K, nb);
    bucket_scan_kernel<<<R, 256, 0, stream>>>(gcnt, bptr, K);

    int spmm_blocks = (N + 3) / 4;
    int masked_blocks = (2 * Bn + 3) / 4;
    for (int r = 0; r < R; r++) {
        const int* rows_r = rows + (size_t)r * E;
        const int* cols_r = cols + (size_t)r * E;
        const float* vals_r = vals + (size_t)r * E;
        const int* bptr_r = bptr + (size_t)r * (K + 1);
        const int* blockBase_r = blockBase + (size_t)r * nb * K;
        int* rp_r = row_ptr + (size_t)r * (N + 1);

        bucket_scatter_kernel<<<nb, 1024, 0, stream>>>(rows_r, cols_r, vals_r,
                                                       bptr_r, blockBase_r, rec,
                                                       E, K, nb);
        bucket_sort_kernel<<<K, 256, 0, stream>>>(rec, srec, bptr_r, rp_r, K, N);

        mlp_kernel<<<(N + 63) / 64, 256, 0, stream>>>(user_emb, item_emb, W1, W2,
                                                      c1_all, b2, bufA, out_acc,
                                                      flag, r, N, U, (r == 0) ? 1 : 0);

        spmm_kernel<<<spmm_blocks, 256, 0, stream>>>(bufA, bufB, out_acc, rp_r,
                                                     srec, flag, N);
        spmm_kernel<<<spmm_blocks, 256, 0, stream>>>(bufB, bufA, out_acc, rp_r,
                                                     srec, flag, N);
        spmm_masked_kernel<<<masked_blocks, 256, 0, stream>>>(bufA, out_acc, rp_r,
                                                              srec, maskbits,
                                                              flist, fcount);
    }

    float scale = 1.0f / (float)(R * R);
    dot_kernel<<<(Bn * 64 + 255) / 256, 256, 0, stream>>>(out_acc, users, items, out,
                                                          Bn, U, scale);
}

// Round 13
// 997.191 us; speedup vs baseline: 1.1426x; 1.0733x over previous
//
#include <hip/hip_runtime.h>
#include <hip/hip_bf16.h>
#include <cstdint>
#include <cstddef>

#define KEYSHIFT 20
#define COLMASK 0xFFFFFu
#define EPB 16384   // edges per count/scatter block (1024 threads x 16)

// ---------------------------------------------------------------------------
// Host-side reproduction of np.random.RandomState(2).permutation(64):
// MT19937 init_genrand(2), Fisher-Yates with numpy random_interval
// (mask+rejection). Mask bit d = (perm[d] >= 38).
// ---------------------------------------------------------------------------
static uint64_t compute_mask_bits() {
    uint32_t mt[624];
    mt[0] = 2u;
    for (int i = 1; i < 624; i++)
        mt[i] = 1812433253u * (mt[i - 1] ^ (mt[i - 1] >> 30)) + (uint32_t)i;
    int mti = 624;
    auto genrand = [&]() -> uint32_t {
        if (mti >= 624) {
            for (int k = 0; k < 624; k++) {
                uint32_t y = (mt[k] & 0x80000000u) | (mt[(k + 1) % 624] & 0x7fffffffu);
                mt[k] = mt[(k + 397) % 624] ^ (y >> 1) ^ ((y & 1u) ? 2567483615u : 0u);
            }
            mti = 0;
        }
        uint32_t y = mt[mti++];
        y ^= y >> 11;
        y ^= (y << 7) & 2636928640u;
        y ^= (y << 15) & 4022730752u;
        y ^= y >> 18;
        return y;
    };
    int arr[64];
    for (int i = 0; i < 64; i++) arr[i] = i;
    for (int i = 63; i >= 1; i--) {
        uint32_t mask = (uint32_t)i;
        mask |= mask >> 1; mask |= mask >> 2; mask |= mask >> 4;
        mask |= mask >> 8; mask |= mask >> 16;
        uint32_t v;
        do { v = genrand() & mask; } while (v > (uint32_t)i);
        int tmp = arr[i]; arr[i] = arr[v]; arr[v] = tmp;
    }
    uint64_t bits = 0;
    for (int d = 0; d < 64; d++)
        if (arr[d] >= 38) bits |= (1ull << d);
    return bits;
}

// ---------------------------------------------------------------------------
// Output-row flag set + compacted list (rows read by the final dot).
// ---------------------------------------------------------------------------
__global__ void flag_kernel(const int* __restrict__ users, const int* __restrict__ items,
                            unsigned char* __restrict__ flag, int B, int U) {
    int i = blockIdx.x * 256 + threadIdx.x;
    if (i < B) flag[users[i]] = 1;
    else if (i < 2 * B) flag[U + items[i - B]] = 1;
}

__global__ void flist_kernel(const unsigned char* __restrict__ flag,
                             int* __restrict__ flist, int* __restrict__ fcount, int n) {
    int i = blockIdx.x * 256 + threadIdx.x;
    if (i < n && flag[i]) {
        int p = atomicAdd(fcount, 1);
        flist[p] = i;
    }
}

// ---------------------------------------------------------------------------
// Per-rating constant c1[r][j] = b1[r][j] + sum_k e_r[k] * W1[r][64+k][j].
// ---------------------------------------------------------------------------
__global__ void c1_kernel(const float* __restrict__ rating_emb, const float* __restrict__ W1,
                          const float* __restrict__ b1, float* __restrict__ c1_all) {
    int r = blockIdx.x;
    int t = threadIdx.x;  // 64 threads
    const float* W1r = W1 + (size_t)r * (128 * 64);
    float acc = b1[r * 64 + t];
    for (int k = 0; k < 64; k++)
        acc += rating_emb[r * 64 + k] * W1r[(64 + k) * 64 + t];
    c1_all[r * 64 + t] = acc;
}

// ---------------------------------------------------------------------------
// Build pass A (batched over ratings): LDS histogram over K=ceil(N/64) row
// buckets, then ONE global atomicAdd per (block,bucket) to reserve a range.
// (global-atomic count is the cost driver: each device-scope atomic is a
// ~32B write-through at its homed L2 -- R7/R9 lesson.)
// ---------------------------------------------------------------------------
__global__ __launch_bounds__(1024) void bucket_count_kernel(
    const int* __restrict__ rows, int* __restrict__ gcnt,
    int* __restrict__ blockBase, int E, int K, int nb) {
    __shared__ int hist[2048];
    int r = blockIdx.y, blk = blockIdx.x, t = threadIdx.x;
    for (int i = t; i < K; i += 1024) hist[i] = 0;
    __syncthreads();
    size_t base = (size_t)r * E + (size_t)blk * EPB;
    int cnt = E - blk * EPB;
    if (cnt > EPB) cnt = EPB;
    for (int k = t; k < cnt; k += 1024)
        atomicAdd(&hist[rows[base + k] >> 6], 1);
    __syncthreads();
    for (int i = t; i < K; i += 1024) {
        int c = hist[i];
        int bb = (c > 0) ? atomicAdd(&gcnt[r * K + i], c) : 0;
        blockBase[((size_t)r * nb + blk) * K + i] = bb;
    }
}

// ---------------------------------------------------------------------------
// Exclusive scan of K bucket counts -> bptr[K+1] per rating (grid.x = R).
// ---------------------------------------------------------------------------
__global__ void bucket_scan_kernel(const int* __restrict__ gcnt,
                                   int* __restrict__ bptr, int K) {
    __shared__ int sh[256];
    int r = blockIdx.x;
    int t = threadIdx.x;
    int base = t * 8;
    int v[8];
    int s = 0;
    #pragma unroll
    for (int j = 0; j < 8; j++) {
        int idx = base + j;
        v[j] = (idx < K) ? gcnt[r * K + idx] : 0;
        s += v[j];
    }
    sh[t] = s;
    __syncthreads();
    for (int off = 1; off < 256; off <<= 1) {
        int x = (t >= off) ? sh[t - off] : 0;
        __syncthreads();
        sh[t] += x;
        __syncthreads();
    }
    int run = sh[t] - s;
    #pragma unroll
    for (int j = 0; j < 8; j++) {
        int idx = base + j;
        if (idx <= K) bptr[r * (K + 1) + idx] = run;
        run += v[j];
    }
}

// ---------------------------------------------------------------------------
// Build pass B: atomic-free scatter into bucket-grouped rec.
// Position = bptr[bucket] + blockBase[blk][bucket] + LDS-cursor rank.
// Stride-parameterized: batched mode launches grid.y=R with real strides;
// fallback launches grid.y=1 with pre-offset pointers and strides 0.
// ---------------------------------------------------------------------------
__global__ __launch_bounds__(1024) void bucket_scatter_kernel(
    const int* __restrict__ rows, const int* __restrict__ cols,
    const float* __restrict__ vals, const int* __restrict__ bptr,
    const int* __restrict__ blockBase, uint2* __restrict__ rec,
    int E, int K, long long eStride, long long pStride,
    long long bbStride, long long rStride) {
    __shared__ int cursor[2048];
    int r = blockIdx.y;
    const int* rows_r = rows + (size_t)r * eStride;
    const int* cols_r = cols + (size_t)r * eStride;
    const float* vals_r = vals + (size_t)r * eStride;
    const int* bptr_r = bptr + (size_t)r * pStride;
    const int* bb_r = blockBase + (size_t)r * bbStride;
    uint2* rec_r = rec + (size_t)r * rStride;
    int blk = blockIdx.x, t = threadIdx.x;
    for (int i = t; i < K; i += 1024)
        cursor[i] = bptr_r[i] + bb_r[(size_t)blk * K + i];
    __syncthreads();
    size_t base = (size_t)blk * EPB;
    int cnt = E - blk * EPB;
    if (cnt > EPB) cnt = EPB;
    for (int k = t; k < cnt; k += 1024) {
        int row = rows_r[base + k];
        int b = row >> 6;
        int pos = atomicAdd(&cursor[b], 1);
        uint32_t key = ((uint32_t)(row & 63) << KEYSHIFT) | (uint32_t)cols_r[base + k];
        rec_r[pos] = make_uint2(key, __float_as_uint(vals_r[base + k]));
    }
}

// ---------------------------------------------------------------------------
// Build pass C: per-bucket counting sort by rel-row: rec -> srec row-sorted;
// emits row_ptr (rating-local offsets). Stride-parameterized like pass B.
// ---------------------------------------------------------------------------
__global__ __launch_bounds__(256) void bucket_sort_kernel(
    const uint2* __restrict__ rec, uint2* __restrict__ srec,
    const int* __restrict__ bptr, int* __restrict__ rp, int K, int N,
    long long rStride, long long pStride, long long rpStride) {
    __shared__ int hist[64];
    __shared__ int excl[64];
    int r = blockIdx.y;
    const uint2* rec_r = rec + (size_t)r * rStride;
    uint2* srec_r = srec + (size_t)r * rStride;
    const int* bptr_r = bptr + (size_t)r * pStride;
    int* rp_r = rp + (size_t)r * rpStride;
    int b = blockIdx.x;
    int t = threadIdx.x;
    if (t < 64) hist[t] = 0;
    __syncthreads();
    int start = bptr_r[b], end = bptr_r[b + 1];
    for (int e = start + t; e < end; e += 256) {
        uint2 rr = rec_r[e];
        atomicAdd(&hist[rr.x >> KEYSHIFT], 1);
    }
    __syncthreads();
    if (t == 0) {
        int run = 0;
        #pragma unroll
        for (int i = 0; i < 64; i++) { excl[i] = run; run += hist[i]; }
    }
    __syncthreads();
    if (t < 64) {
        int row = b * 64 + t;
        if (row < N) rp_r[row] = start + excl[t];
        hist[t] = 0;  // reuse as cursors
    }
    if (b == K - 1 && t == 0) rp_r[N] = bptr_r[K];
    __syncthreads();
    for (int e = start + t; e < end; e += 256) {
        uint2 rr = rec_r[e];
        int rel = (int)(rr.x >> KEYSHIFT);
        int pos = start + excl[rel] + atomicAdd(&hist[rel], 1);
        srec_r[pos] = rr;
    }
}

// ---------------------------------------------------------------------------
// Per-rating MLP: h = leaky_relu(x @ W1a + c1) @ W2 + b2
// LDS: one W tile + one X/T tile (reused) = 33 KB; 16B-group XOR swizzle
// keeps all LDS streams conflict-free. prev = h; out_acc (flagged rows):
// init ? store : RMW-add (init at r=0 replaces the 25.6MB memset).
// ---------------------------------------------------------------------------
__global__ __launch_bounds__(256) void mlp_kernel(
    const float* __restrict__ user_emb, const float* __restrict__ item_emb,
    const float* __restrict__ W1, const float* __restrict__ W2,
    const float* __restrict__ c1_all, const float* __restrict__ b2,
    float* __restrict__ prev, float* __restrict__ out_acc,
    const unsigned char* __restrict__ flag, int r, int n_rows, int U, int init) {
    __shared__ float sW[64 * 64];   // [k][j], linear
    __shared__ float sX[64 * 64];   // [k][i], group-swizzled; reused for T
    __shared__ float sc1[64];
    __shared__ float sb2v[64];

    int t = threadIdx.x;
    int row0 = blockIdx.x * 64;
    const float* W1r = W1 + (size_t)r * (128 * 64);
    const float* W2r = W2 + (size_t)r * (64 * 64);

    #pragma unroll
    for (int q = 0; q < 4; q++) {
        int f = t + 256 * q;
        int k = f >> 4, c = (f & 15) * 4;
        *(float4*)(sW + k * 64 + c) = *(const float4*)(W1r + k * 64 + c);
    }
    #pragma unroll
    for (int q = 0; q < 4; q++) {
        int f = t + 256 * q;
        int i = f & 63;
        int c = (f >> 6) * 4;
        int nrow = row0 + i;
        float4 xv = make_float4(0.f, 0.f, 0.f, 0.f);
        if (nrow < n_rows) {
            const float* src = (nrow < U) ? (user_emb + (size_t)nrow * 64)
                                          : (item_emb + (size_t)(nrow - U) * 64);
            xv = *(const float4*)(src + c);
        }
        int gi = i >> 2, w = i & 3;
        sX[(c + 0) * 64 + 4 * (gi ^ ((c + 0) & 15)) + w] = xv.x;
        sX[(c + 1) * 64 + 4 * (gi ^ ((c + 1) & 15)) + w] = xv.y;
        sX[(c + 2) * 64 + 4 * (gi ^ ((c + 2) & 15)) + w] = xv.z;
        sX[(c + 3) * 64 + 4 * (gi ^ ((c + 3) & 15)) + w] = xv.w;
    }
    if (t < 64) sc1[t] = c1_all[r * 64 + t];
    else if (t < 128) sb2v[t - 64] = b2[r * 64 + (t - 64)];
    __syncthreads();

    int gi = t & 15;
    int i0 = gi * 4, j0 = (t >> 4) * 4;
    float acc[4][4];
    #pragma unroll
    for (int a = 0; a < 4; a++)
        #pragma unroll
        for (int b = 0; b < 4; b++) acc[a][b] = sc1[j0 + b];
    for (int k = 0; k < 64; k++) {
        float4 xv = *(const float4*)(sX + k * 64 + 4 * (gi ^ (k & 15)));
        float4 wv = *(const float4*)(sW + k * 64 + j0);
        float xs[4] = {xv.x, xv.y, xv.z, xv.w};
        float ws[4] = {wv.x, wv.y, wv.z, wv.w};
        #pragma unroll
        for (int a = 0; a < 4; a++)
            #pragma unroll
            for (int b = 0; b < 4; b++) acc[a][b] += xs[a] * ws[b];
    }
    __syncthreads();

    #pragma unroll
    for (int b = 0; b < 4; b++) {
        int k = j0 + b;
        float4 tv;
        tv.x = (acc[0][b] >= 0.f) ? acc[0][b] : 0.01f * acc[0][b];
        tv.y = (acc[1][b] >= 0.f) ? acc[1][b] : 0.01f * acc[1][b];
        tv.z = (acc[2][b] >= 0.f) ? acc[2][b] : 0.01f * acc[2][b];
        tv.w = (acc[3][b] >= 0.f) ? acc[3][b] : 0.01f * acc[3][b];
        *(float4*)(sX + k * 64 + 4 * (gi ^ (k & 15))) = tv;
    }
    #pragma unroll
    for (int q = 0; q < 4; q++) {
        int f = t + 256 * q;
        int k = f >> 4, c = (f & 15) * 4;
        *(float4*)(sW + k * 64 + c) = *(const float4*)(W2r + k * 64 + c);
    }
    __syncthreads();

    #pragma unroll
    for (int a = 0; a < 4; a++)
        #pragma unroll
        for (int b = 0; b < 4; b++) acc[a][b] = sb2v[j0 + b];
    for (int k = 0; k < 64; k++) {
        float4 xv = *(const float4*)(sX + k * 64 + 4 * (gi ^ (k & 15)));
        float4 wv = *(const float4*)(sW + k * 64 + j0);
        float xs[4] = {xv.x, xv.y, xv.z, xv.w};
        float ws[4] = {wv.x, wv.y, wv.z, wv.w};
        #pragma unroll
        for (int a = 0; a < 4; a++)
            #pragma unroll
            for (int b = 0; b < 4; b++) acc[a][b] += xs[a] * ws[b];
    }
    #pragma unroll
    for (int a = 0; a < 4; a++) {
        int nrow = row0 + i0 + a;
        if (nrow < n_rows) {
            float4 hv = make_float4(acc[a][0], acc[a][1], acc[a][2], acc[a][3]);
            *(float4*)(prev + (size_t)nrow * 64 + j0) = hv;
            if (flag[nrow]) {
                float* o = out_acc + (size_t)nrow * 64 + j0;
                if (init) {
                    *(float4*)o = hv;
                } else {
                    float4 ov = *(const float4*)o;
                    ov.x += hv.x; ov.y += hv.y; ov.z += hv.z; ov.w += hv.w;
                    *(float4*)o = ov;
                }
            }
        }
    }
}

// ---------------------------------------------------------------------------
// Gather-SpMM (layers 0/1): wave = 1 row; 4 edge-groups x 16 lanes x float4
// (full 256B row consumed per gather). 8 edges in flight per wave.
// R10/R12 proven form: plain uint2 loads, plain float4 store.
// ---------------------------------------------------------------------------
__global__ __launch_bounds__(256) void spmm_kernel(
    const float* __restrict__ prev, float* __restrict__ next,
    float* __restrict__ out_acc, const int* __restrict__ rp,
    const uint2* __restrict__ rec, const unsigned char* __restrict__ flag, int n) {
    int wave = (int)((blockIdx.x * (unsigned)blockDim.x + threadIdx.x) >> 6);
    int lane = threadIdx.x & 63;
    if (wave >= n) return;
    int sub = lane >> 4;      // edge group 0..3
    int dl = lane & 15;       // dims [dl*4, dl*4+4)
    int s = rp[wave], e2 = rp[wave + 1];
    float ax = 0.f, ay = 0.f, az = 0.f, aw = 0.f;
    int e = s + sub;
    for (; e + 4 < e2; e += 8) {
        uint2 r0 = rec[e];
        uint2 r1 = rec[e + 4];
        float4 p0 = *(const float4*)(prev + (size_t)(r0.x & COLMASK) * 64 + dl * 4);
        float4 p1 = *(const float4*)(prev + (size_t)(r1.x & COLMASK) * 64 + dl * 4);
        float v0 = __uint_as_float(r0.y), v1 = __uint_as_float(r1.y);
        ax += v0 * p0.x; ay += v0 * p0.y; az += v0 * p0.z; aw += v0 * p0.w;
        ax += v1 * p1.x; ay += v1 * p1.y; az += v1 * p1.z; aw += v1 * p1.w;
    }
    if (e < e2) {
        uint2 r0 = rec[e];
        float4 p0 = *(const float4*)(prev + (size_t)(r0.x & COLMASK) * 64 + dl * 4);
        float v0 = __uint_as_float(r0.y);
        ax += v0 * p0.x; ay += v0 * p0.y; az += v0 * p0.z; aw += v0 * p0.w;
    }
    ax += __shfl_xor(ax, 16); ay += __shfl_xor(ay, 16);
    az += __shfl_xor(az, 16); aw += __shfl_xor(aw, 16);
    ax += __shfl_xor(ax, 32); ay += __shfl_xor(ay, 32);
    az += __shfl_xor(az, 32); aw += __shfl_xor(aw, 32);
    if (sub == 0) {
        *(float4*)(next + (size_t)wave * 64 + dl * 4) = make_float4(ax, ay, az, aw);
    } else if (sub == 1 && flag[wave]) {
        float* o = out_acc + (size_t)wave * 64 + dl * 4;
        float4 ov = *(const float4*)o;
        ov.x += ax; ov.y += ay; ov.z += az; ov.w += aw;
        *(float4*)o = ov;
    }
}

// ---------------------------------------------------------------------------
// Layer-2 (masked) SpMM: only rows in flist. Same float4-lane layout.
// ---------------------------------------------------------------------------
__global__ __launch_bounds__(256) void spmm_masked_kernel(
    const float* __restrict__ prev, float* __restrict__ out_acc,
    const int* __restrict__ rp, const uint2* __restrict__ rec,
    unsigned long long maskbits, const int* __restrict__ flist,
    const int* __restrict__ fcount) {
    int w = (int)((blockIdx.x * (unsigned)blockDim.x + threadIdx.x) >> 6);
    int lane = threadIdx.x & 63;
    if (w >= *fcount) return;
    int sub = lane >> 4;
    int dl = lane & 15;
    int row = flist[w];
    int s = rp[row], e2 = rp[row + 1];
    float ax = 0.f, ay = 0.f, az = 0.f, aw = 0.f;
    int e = s + sub;
    for (; e + 4 < e2; e += 8) {
        uint2 r0 = rec[e];
        uint2 r1 = rec[e + 4];
        float4 p0 = *(const float4*)(prev + (size_t)(r0.x & COLMASK) * 64 + dl * 4);
        float4 p1 = *(const float4*)(prev + (size_t)(r1.x & COLMASK) * 64 + dl * 4);
        float v0 = __uint_as_float(r0.y), v1 = __uint_as_float(r1.y);
        ax += v0 * p0.x; ay += v0 * p0.y; az += v0 * p0.z; aw += v0 * p0.w;
        ax += v1 * p1.x; ay += v1 * p1.y; az += v1 * p1.z; aw += v1 * p1.w;
    }
    if (e < e2) {
        uint2 r0 = rec[e];
        float4 p0 = *(const float4*)(prev + (size_t)(r0.x & COLMASK) * 64 + dl * 4);
        float v0 = __uint_as_float(r0.y);
        ax += v0 * p0.x; ay += v0 * p0.y; az += v0 * p0.z; aw += v0 * p0.w;
    }
    ax += __shfl_xor(ax, 16); ay += __shfl_xor(ay, 16);
    az += __shfl_xor(az, 16); aw += __shfl_xor(aw, 16);
    ax += __shfl_xor(ax, 32); ay += __shfl_xor(ay, 32);
    az += __shfl_xor(az, 32); aw += __shfl_xor(aw, 32);
    if (sub == 0) {
        const float* pv = prev + (size_t)row * 64 + dl * 4;
        float4 pvv = *(const float4*)pv;
        float rx = ((maskbits >> (dl * 4 + 0)) & 1ull) ? ax : pvv.x;
        float ry = ((maskbits >> (dl * 4 + 1)) & 1ull) ? ay : pvv.y;
        float rz = ((maskbits >> (dl * 4 + 2)) & 1ull) ? az : pvv.z;
        float rw = ((maskbits >> (dl * 4 + 3)) & 1ull) ? aw : pvv.w;
        float* o = out_acc + (size_t)row * 64 + dl * 4;
        float4 ov = *(const float4*)o;
        ov.x += rx; ov.y += ry; ov.z += rz; ov.w += rw;
        *(float4*)o = ov;
    }
}

// ---------------------------------------------------------------------------
// Final: out[b] = (1/R^2) * dot(out_acc[users[b]], out_acc[U+items[b]])
// ---------------------------------------------------------------------------
__global__ __launch_bounds__(256) void dot_kernel(
    const float* __restrict__ out_acc, const int* __restrict__ users,
    const int* __restrict__ items, float* __restrict__ out,
    int Bn, int U, float scale) {
    int w = (int)((blockIdx.x * (unsigned)blockDim.x + threadIdx.x) >> 6);
    int lane = threadIdx.x & 63;
    if (w >= Bn) return;
    int u = users[w], it = items[w];
    float a = out_acc[(size_t)u * 64 + lane];
    float c = out_acc[((size_t)(U + it)) * 64 + lane];
    float p = a * c;
    #pragma unroll
    for (int off = 32; off > 0; off >>= 1) p += __shfl_down(p, off);
    if (lane == 0) out[w] = p * scale;
}

// ---------------------------------------------------------------------------
extern "C" void kernel_launch(void* const* d_in, const int* in_sizes, int n_in,
                              void* d_out, int out_size, void* d_ws, size_t ws_size,
                              hipStream_t stream) {
    const int* users = (const int*)d_in[0];
    const int* items = (const int*)d_in[1];
    const float* user_emb = (const float*)d_in[2];
    const float* item_emb = (const float*)d_in[3];
    const float* rating_emb = (const float*)d_in[4];
    const float* W1 = (const float*)d_in[5];
    const float* b1 = (const float*)d_in[6];
    const float* W2 = (const float*)d_in[7];
    const float* b2 = (const float*)d_in[8];
    const int* rows = (const int*)d_in[9];
    const int* cols = (const int*)d_in[10];
    const float* vals = (const float*)d_in[11];
    float* out = (float*)d_out;

    const int Dd = 64;
    int U = in_sizes[2] / Dd;
    int I = in_sizes[3] / Dd;
    int R = in_sizes[4] / Dd;
    int N = U + I;
    int E = in_sizes[9] / R;
    int Bn = in_sizes[0];
    int K = (N + 63) / 64;          // row buckets; K+1 <= 2048
    int nb = (E + EPB - 1) / EPB;   // count/scatter blocks per rating

    auto al = [](size_t b) { return (b + 255) & ~(size_t)255; };
    size_t base_need = 3 * al((size_t)N * 64 * 4) + al((size_t)R * K * 4)
        + al((size_t)R * (K + 1) * 4) + al((size_t)R * nb * K * 4)
        + al((size_t)R * (N + 1) * 4) + al((size_t)R * 64 * 4)
        + al((size_t)N) + al((size_t)2 * Bn * 4) + al(4);
    size_t rec_one = al((size_t)E * 8);
    size_t rec_all = al((size_t)E * 8 * R);
    // Batched build needs rec+srec for all R ratings simultaneously.
    int batched = (ws_size >= base_need + 2 * rec_all + 65536) ? 1 : 0;
    size_t recsz = batched ? rec_all : rec_one;

    char* p = (char*)d_ws;
    auto carve = [&](size_t bytes) -> char* {
        char* q = p;
        p += (bytes + 255) & ~(size_t)255;
        return q;
    };
    float* out_acc = (float*)carve((size_t)N * 64 * 4);
    float* bufA = (float*)carve((size_t)N * 64 * 4);
    float* bufB = (float*)carve((size_t)N * 64 * 4);
    uint2* rec = (uint2*)carve(recsz);
    uint2* srec = (uint2*)carve(recsz);
    int* gcnt = (int*)carve((size_t)R * K * 4);
    int* bptr = (int*)carve((size_t)R * (K + 1) * 4);
    int* blockBase = (int*)carve((size_t)R * nb * K * 4);
    int* row_ptr = (int*)carve((size_t)R * (N + 1) * 4);
    float* c1_all = (float*)carve((size_t)R * 64 * 4);
    unsigned char* flag = (unsigned char*)carve((size_t)N);
    int* flist = (int*)carve((size_t)2 * Bn * 4);
    int* fcount = (int*)carve(4);

    uint64_t maskbits = compute_mask_bits();

    hipMemsetAsync(flag, 0, (size_t)N, stream);
    hipMemsetAsync(fcount, 0, 4, stream);
    hipMemsetAsync(gcnt, 0, (size_t)R * K * 4, stream);

    flag_kernel<<<(2 * Bn + 255) / 256, 256, 0, stream>>>(users, items, flag, Bn, U);
    flist_kernel<<<(N + 255) / 256, 256, 0, stream>>>(flag, flist, fcount, N);
    c1_kernel<<<R, 64, 0, stream>>>(rating_emb, W1, b1, c1_all);

    // Build pass A (batched over ratings) + per-rating scans
    dim3 cgrid(nb, R);
    bucket_count_kernel<<<cgrid, 1024, 0, stream>>>(rows, gcnt, blockBase, E, K, nb);
    bucket_scan_kernel<<<R, 256, 0, stream>>>(gcnt, bptr, K);

    if (batched) {
        // Scatter + sort for ALL ratings in two launches (5x scatter
        // parallelism: 61 blocks/rating alone leaves the device ~75% idle).
        dim3 sgrid(nb, R);
        bucket_scatter_kernel<<<sgrid, 1024, 0, stream>>>(
            rows, cols, vals, bptr, blockBase, rec, E, K,
            (long long)E, (long long)(K + 1), (long long)nb * K, (long long)E);
        dim3 ogrid(K, R);
        bucket_sort_kernel<<<ogrid, 256, 0, stream>>>(
            rec, srec, bptr, row_ptr, K, N,
            (long long)E, (long long)(K + 1), (long long)(N + 1));
    }

    int spmm_blocks = (N + 3) / 4;
    int masked_blocks = (2 * Bn + 3) / 4;
    for (int r = 0; r < R; r++) {
        const int* bptr_r = bptr + (size_t)r * (K + 1);
        int* rp_r = row_ptr + (size_t)r * (N + 1);
        uint2* srec_r = batched ? (srec + (size_t)r * E) : srec;

        if (!batched) {
            dim3 sgrid(nb, 1);
            bucket_scatter_kernel<<<sgrid, 1024, 0, stream>>>(
                rows + (size_t)r * E, cols + (size_t)r * E, vals + (size_t)r * E,
                bptr_r, blockBase + (size_t)r * nb * K, rec, E, K, 0, 0, 0, 0);
            dim3 ogrid(K, 1);
            bucket_sort_kernel<<<ogrid, 256, 0, stream>>>(
                rec, srec, bptr_r, rp_r, K, N, 0, 0, 0);
        }

        mlp_kernel<<<(N + 63) / 64, 256, 0, stream>>>(user_emb, item_emb, W1, W2,
                                                      c1_all, b2, bufA, out_acc,
                                                      flag, r, N, U, (r == 0) ? 1 : 0);

        spmm_kernel<<<spmm_blocks, 256, 0, stream>>>(bufA, bufB, out_acc, rp_r,
                                                     srec_r, flag, N);
        spmm_kernel<<<spmm_blocks, 256, 0, stream>>>(bufB, bufA, out_acc, rp_r,
                                                     srec_r, flag, N);
        spmm_masked_kernel<<<masked_blocks, 256, 0, stream>>>(bufA, out_acc, rp_r,
                                                              srec_r, maskbits,
                                                              flist, fcount);
    }

    float scale = 1.0f / (float)(R * R);
    dot_kernel<<<(Bn * 64 + 255) / 256, 256, 0, stream>>>(out_acc, users, items, out,
                                                          Bn, U, scale);
}